// Round 6
// baseline (113.475 us; speedup 1.0000x reference)
//
#include <hip/hip_runtime.h>
#include <math.h>

// PointsGeneration: elementwise sigmoid + threshold-gated regression concat.
//
// R5: 16 KB contiguous runs per stream visit (16 back-to-back dwordx4 per
// plane per wave; R4's 8 KB runs gave +11% over 1 KB interleave, pursuing
// the DRAM row-locality gradient). Score planes processed ONE AT A TIME to
// bound live registers (16 x f32x4 = 64 VGPR); threshold state carried in
// per-thread 64-bit pixel masks (64 px/thread).
// Grid: 1024 waves (256 blocks x 256 thr) = 4 waves/CU; in-flight bytes
// 1024 x 16 KB = 16 MB >> BW*latency (~2.4 MB), latency hiding preserved.

typedef float f32x4 __attribute__((ext_vector_type(4)));
typedef unsigned long long u64;

static __device__ __forceinline__ float sigf(float x) {
    // Accurate fp32 sigmoid (expf, not __expf): threshold comparisons sit on
    // the sigmoid value; match the numpy fp32 reference to avoid mask flips.
    return 1.0f / (1.0f + expf(-x));
}

static __device__ __forceinline__ f32x4 ld4(const float* p) {
    return *reinterpret_cast<const f32x4*>(p);
}
static __device__ __forceinline__ void st4(float* p, f32x4 v) {
    *reinterpret_cast<f32x4*>(p) = v;
}

// Sigmoid one score plane's 16 KB window, store it, return 64-bit mask of
// (sigmoid > thr) per pixel (bit 4*j+k for vector j, component k).
static __device__ __forceinline__ u64 score_plane(
    const float* __restrict__ src, float* __restrict__ dst,
    float thr, int base)
{
    f32x4 V[16];
#pragma unroll
    for (int j = 0; j < 16; ++j) V[j] = ld4(src + base + j * 256);
    u64 m = 0;
#pragma unroll
    for (int j = 0; j < 16; ++j) {
#pragma unroll
        for (int k = 0; k < 4; ++k) {
            V[j][k] = sigf(V[j][k]);
            if (V[j][k] > thr) m |= 1ull << (4 * j + k);
        }
    }
#pragma unroll
    for (int j = 0; j < 16; ++j) st4(dst + base + j * 256, V[j]);
    return m;
}

// Gate one regression channel's 16 KB window by mask m.
static __device__ __forceinline__ void reg_plane(
    const float* __restrict__ src, float* __restrict__ dst,
    u64 m, int base)
{
    f32x4 V[16];
#pragma unroll
    for (int j = 0; j < 16; ++j) V[j] = ld4(src + base + j * 256);
#pragma unroll
    for (int j = 0; j < 16; ++j) {
#pragma unroll
        for (int k = 0; k < 4; ++k) {
            V[j][k] = ((m >> (4 * j + k)) & 1ull) ? V[j][k] : 0.0f;
        }
    }
#pragma unroll
    for (int j = 0; j < 16; ++j) st4(dst + base + j * 256, V[j]);
}

__global__ __launch_bounds__(256) void points_gen_kernel(
    const float* __restrict__ p_text,
    const float* __restrict__ p_head,
    const float* __restrict__ p_tail,
    const float* __restrict__ p_bond,
    const float* __restrict__ p_rh,
    const float* __restrict__ p_rt,
    const float* __restrict__ p_rb,
    float* __restrict__ out)
{
    constexpr int N = 2048 * 2048;   // pixels per plane
    constexpr int WPX = 4096;        // pixels per wave per plane (16 KB)
    const int lane = threadIdx.x & 63;
    const int wave = (blockIdx.x * blockDim.x + threadIdx.x) >> 6;  // 0..1023
    const int base = wave * WPX + lane * 4;   // + j*256 for j in 0..15

    // ---- phase 1: score planes, one at a time (16 KB runs) ----
    const u64 mt = score_plane(p_text, out + 0 * N, 0.45f, base);
    const u64 mh = score_plane(p_head, out + 1 * N, 0.50f, base) & mt;
    const u64 ml = score_plane(p_tail, out + 2 * N, 0.50f, base) & mt;
    const u64 mb = score_plane(p_bond, out + 3 * N, 0.50f, base);

    // ---- phase 2: gated regression channels (16 KB runs each) ----
#pragma unroll
    for (int c = 0; c < 4; ++c)
        reg_plane(p_rh + c * N, out + (4 + c) * N, mh, base);
#pragma unroll
    for (int c = 0; c < 4; ++c)
        reg_plane(p_rt + c * N, out + (8 + c) * N, ml, base);
#pragma unroll
    for (int c = 0; c < 4; ++c)
        reg_plane(p_rb + c * N, out + (12 + c) * N, mb, base);
}

extern "C" void kernel_launch(void* const* d_in, const int* in_sizes, int n_in,
                              void* d_out, int out_size, void* d_ws, size_t ws_size,
                              hipStream_t stream) {
    (void)in_sizes; (void)n_in; (void)out_size; (void)d_ws; (void)ws_size;

    const float* p_text = (const float*)d_in[0];
    const float* p_head = (const float*)d_in[1];
    const float* p_tail = (const float*)d_in[2];
    const float* p_bond = (const float*)d_in[3];
    const float* p_rh   = (const float*)d_in[4];
    const float* p_rt   = (const float*)d_in[5];
    const float* p_rb   = (const float*)d_in[6];
    float* out = (float*)d_out;

    constexpr int N = 2048 * 2048;
    constexpr int WPX = 4096;                       // pixels per wave per plane
    constexpr int waves = N / WPX;                  // 1024
    constexpr int threads = 256;                    // 4 waves per block
    constexpr int blocks = waves * 64 / threads;    // 256

    points_gen_kernel<<<blocks, threads, 0, stream>>>(
        p_text, p_head, p_tail, p_bond, p_rh, p_rt, p_rb, out);
}